// Round 4
// 2281.162 us; speedup vs baseline: 10.4601x; 10.4601x over previous
//
#include <hip/hip_runtime.h>

#define D 128
#define M 64

__global__ __launch_bounds__(256, 2) void gmm_kernel(
    const float* __restrict__ x, const float* __restrict__ mem,
    const float* __restrict__ gw, const float* __restrict__ gb,
    float* __restrict__ out, int n)
{
    __shared__ float smem[M * D];   // 32 KB: full memory matrix, row-major
    __shared__ float sgw[D];

    // cooperative staging: 8192 floats = 2048 float4 over 256 threads
    for (int i = threadIdx.x; i < (M * D) / 4; i += 256)
        ((float4*)smem)[i] = ((const float4*)mem)[i];
    if (threadIdx.x < D / 4)
        ((float4*)sgw)[threadIdx.x] = ((const float4*)gw)[threadIdx.x];
    __syncthreads();

    int row = blockIdx.x * 256 + threadIdx.x;
    if (row >= n) return;   // no __syncthreads after this point

    const float4* __restrict__ xr = (const float4*)(x + (size_t)row * D);
    float4* __restrict__ outr = (float4*)(out + (size_t)row * D);
    const float gbias = gb[0];

    float sim[M];           // must stay in registers: 64 VGPRs
#pragma unroll
    for (int m = 0; m < M; ++m) sim[m] = 0.0f;
    float g0 = 0.f, g1 = 0.f, g2 = 0.f, g3 = 0.f;

    // ---- pass 1: sim[m] = x . mem[m], gate partials ----
    // chunks of 16 dims (4 float4) to keep live set ~110 VGPRs; c-loop kept
    // rolled to bound code size (full unroll would be ~20K instrs).
#pragma unroll 1
    for (int c = 0; c < 8; ++c) {
        float4 xc[4];
#pragma unroll
        for (int j = 0; j < 4; ++j) xc[j] = xr[c * 4 + j];

        const float4* gw4 = (const float4*)sgw + c * 4;
#pragma unroll
        for (int j = 0; j < 4; ++j) {
            float4 w = gw4[j];
            g0 += xc[j].x * w.x; g1 += xc[j].y * w.y;
            g2 += xc[j].z * w.z; g3 += xc[j].w * w.w;
        }
        // m innermost: consecutive FMAs hit different sim[m] -> no dep chains
#pragma unroll
        for (int j = 0; j < 4; ++j) {
            const float4* mp = (const float4*)smem + c * 4 + j;
            float4 xv = xc[j];
#pragma unroll
            for (int m = 0; m < M; ++m) {
                float4 v = mp[m * (D / 4)];   // wave-uniform broadcast read
                sim[m] += xv.x * v.x + xv.y * v.y + xv.z * v.z + xv.w * v.w;
            }
        }
    }

    float gate = (g0 + g1) + (g2 + g3) + gbias;
    float g = 1.0f / (1.0f + __expf(-gate));

    // ---- softmax over 64 slots, per-lane ----
    float mx = sim[0];
#pragma unroll
    for (int m = 1; m < M; ++m) mx = fmaxf(mx, sim[m]);
    float sum = 0.0f;
#pragma unroll
    for (int m = 0; m < M; ++m) {
        float e = __expf(sim[m] - mx);
        sim[m] = e;                 // sim now holds unnormalized attn
        sum += e;
    }
    float grs = g / sum;            // fold softmax normalization into gate
    float gi  = 1.0f - g;

    // ---- pass 2: out = grs * (attn_unnorm @ mem) + gi * x ----
#pragma unroll 1
    for (int c = 0; c < 8; ++c) {
        float4 acc[4];
#pragma unroll
        for (int j = 0; j < 4; ++j) acc[j] = make_float4(0.f, 0.f, 0.f, 0.f);
#pragma unroll
        for (int j = 0; j < 4; ++j) {
            const float4* mp = (const float4*)smem + c * 4 + j;
#pragma unroll
            for (int m = 0; m < M; ++m) {
                float4 v = mp[m * (D / 4)];   // broadcast read
                float a = sim[m];
                acc[j].x += a * v.x; acc[j].y += a * v.y;
                acc[j].z += a * v.z; acc[j].w += a * v.w;
            }
        }
#pragma unroll
        for (int j = 0; j < 4; ++j) {
            float4 xv = xr[c * 4 + j];        // re-read x (L2/L3-hot)
            float4 o;
            o.x = grs * acc[j].x + gi * xv.x;
            o.y = grs * acc[j].y + gi * xv.y;
            o.z = grs * acc[j].z + gi * xv.z;
            o.w = grs * acc[j].w + gi * xv.w;
            outr[c * 4 + j] = o;
        }
    }
}

extern "C" void kernel_launch(void* const* d_in, const int* in_sizes, int n_in,
                              void* d_out, int out_size, void* d_ws, size_t ws_size,
                              hipStream_t stream) {
    const float* x   = (const float*)d_in[0];
    const float* mem = (const float*)d_in[1];
    const float* gw  = (const float*)d_in[2];
    const float* gb  = (const float*)d_in[3];
    float* out = (float*)d_out;
    int n = in_sizes[0] / D;   // number of rows

    int grid = (n + 255) / 256;
    gmm_kernel<<<grid, 256, 0, stream>>>(x, mem, gw, gb, out, n);
}

// Round 6
// 1429.982 us; speedup vs baseline: 16.6863x; 1.5952x over previous
//
#include <hip/hip_runtime.h>

#define D 128
#define M 64

// No LDS at all: mem/gw/gb are wave-uniform and read via the SMEM (scalar)
// pipe -- uniform address + uniform control flow + __restrict__ lets the
// compiler select s_load_dwordx4/x16, and v_fma_f32 uses the SGPR operand
// directly. This takes the 64x128 matrix sweep off the LDS pipe (which was
// the Round-4 bottleneck: 4096 ds_read_b128/wave ~ 49K LDS-pipe cycles vs
// 33K VALU cycles, VALUBusy 26%).
__global__ __launch_bounds__(256, 3) void gmm_kernel(
    const float* __restrict__ x, const float* __restrict__ mem,
    const float* __restrict__ gw, const float* __restrict__ gb,
    float* __restrict__ out, int n)
{
    int row = blockIdx.x * 256 + threadIdx.x;
    // Clamp instead of early-return: keeps control flow UNIFORM so scalar
    // loads of mem stay s_load. Clamped threads redundantly recompute row
    // n-1 and store identical bytes (benign).
    if (row >= n) row = n - 1;

    const float4* __restrict__ xr = (const float4*)(x + (size_t)row * D);
    float4* __restrict__ outr = (float4*)(out + (size_t)row * D);
    const float gbias = gb[0];

    float sim[M];                    // 64 VGPRs, statically indexed
#pragma unroll
    for (int m = 0; m < M; ++m) sim[m] = 0.0f;
    float g0 = 0.f, g1 = 0.f, g2 = 0.f, g3 = 0.f;

    // ---- pass 1: sim[m] = x . mem[m], gate partials ----
#pragma unroll 1
    for (int c = 0; c < 8; ++c) {                  // 8 chunks of 16 dims
        float4 xc[4];
#pragma unroll
        for (int j = 0; j < 4; ++j) xc[j] = xr[c * 4 + j];

        const float4* gw4 = (const float4*)(gw + c * 16);   // uniform -> s_load
#pragma unroll
        for (int j = 0; j < 4; ++j) {
            float4 w = gw4[j];
            g0 += xc[j].x * w.x; g1 += xc[j].y * w.y;
            g2 += xc[j].z * w.z; g3 += xc[j].w * w.w;
        }
#pragma unroll
        for (int m = 0; m < M; ++m) {
            const float4* mr = (const float4*)(mem + m * D + c * 16); // uniform
            float4 v0 = mr[0], v1 = mr[1], v2 = mr[2], v3 = mr[3];
            float s = sim[m];
            s = fmaf(xc[0].x, v0.x, s); s = fmaf(xc[0].y, v0.y, s);
            s = fmaf(xc[0].z, v0.z, s); s = fmaf(xc[0].w, v0.w, s);
            s = fmaf(xc[1].x, v1.x, s); s = fmaf(xc[1].y, v1.y, s);
            s = fmaf(xc[1].z, v1.z, s); s = fmaf(xc[1].w, v1.w, s);
            s = fmaf(xc[2].x, v2.x, s); s = fmaf(xc[2].y, v2.y, s);
            s = fmaf(xc[2].z, v2.z, s); s = fmaf(xc[2].w, v2.w, s);
            s = fmaf(xc[3].x, v3.x, s); s = fmaf(xc[3].y, v3.y, s);
            s = fmaf(xc[3].z, v3.z, s); s = fmaf(xc[3].w, v3.w, s);
            sim[m] = s;
        }
    }

    float gate = (g0 + g1) + (g2 + g3) + gbias;
    float g = 1.0f / (1.0f + __expf(-gate));

    // ---- softmax over the 64 slots, per-lane ----
    float mx = sim[0];
#pragma unroll
    for (int m = 1; m < M; ++m) mx = fmaxf(mx, sim[m]);
    float sum = 0.0f;
#pragma unroll
    for (int m = 0; m < M; ++m) {
        float e = __expf(sim[m] - mx);
        sim[m] = e;                  // sim now holds unnormalized attn
        sum += e;
    }
    float grs = g / sum;             // fold softmax normalization into gate
    float gi  = 1.0f - g;

    // ---- pass 2: out = grs * (attn_unnorm @ mem) + gi * x ----
#pragma unroll 1
    for (int c = 0; c < 8; ++c) {
        float4 acc0 = make_float4(0.f, 0.f, 0.f, 0.f);
        float4 acc1 = make_float4(0.f, 0.f, 0.f, 0.f);
        float4 acc2 = make_float4(0.f, 0.f, 0.f, 0.f);
        float4 acc3 = make_float4(0.f, 0.f, 0.f, 0.f);
#pragma unroll
        for (int m = 0; m < M; ++m) {
            const float4* mr = (const float4*)(mem + m * D + c * 16); // uniform
            float4 v0 = mr[0], v1 = mr[1], v2 = mr[2], v3 = mr[3];
            float a = sim[m];
            acc0.x = fmaf(a, v0.x, acc0.x); acc0.y = fmaf(a, v0.y, acc0.y);
            acc0.z = fmaf(a, v0.z, acc0.z); acc0.w = fmaf(a, v0.w, acc0.w);
            acc1.x = fmaf(a, v1.x, acc1.x); acc1.y = fmaf(a, v1.y, acc1.y);
            acc1.z = fmaf(a, v1.z, acc1.z); acc1.w = fmaf(a, v1.w, acc1.w);
            acc2.x = fmaf(a, v2.x, acc2.x); acc2.y = fmaf(a, v2.y, acc2.y);
            acc2.z = fmaf(a, v2.z, acc2.z); acc2.w = fmaf(a, v2.w, acc2.w);
            acc3.x = fmaf(a, v3.x, acc3.x); acc3.y = fmaf(a, v3.y, acc3.y);
            acc3.z = fmaf(a, v3.z, acc3.z); acc3.w = fmaf(a, v3.w, acc3.w);
        }
        float4 xv0 = xr[c * 4 + 0], xv1 = xr[c * 4 + 1];
        float4 xv2 = xr[c * 4 + 2], xv3 = xr[c * 4 + 3];
        float4 o0, o1, o2, o3;
        o0.x = fmaf(grs, acc0.x, gi * xv0.x); o0.y = fmaf(grs, acc0.y, gi * xv0.y);
        o0.z = fmaf(grs, acc0.z, gi * xv0.z); o0.w = fmaf(grs, acc0.w, gi * xv0.w);
        o1.x = fmaf(grs, acc1.x, gi * xv1.x); o1.y = fmaf(grs, acc1.y, gi * xv1.y);
        o1.z = fmaf(grs, acc1.z, gi * xv1.z); o1.w = fmaf(grs, acc1.w, gi * xv1.w);
        o2.x = fmaf(grs, acc2.x, gi * xv2.x); o2.y = fmaf(grs, acc2.y, gi * xv2.y);
        o2.z = fmaf(grs, acc2.z, gi * xv2.z); o2.w = fmaf(grs, acc2.w, gi * xv2.w);
        o3.x = fmaf(grs, acc3.x, gi * xv3.x); o3.y = fmaf(grs, acc3.y, gi * xv3.y);
        o3.z = fmaf(grs, acc3.z, gi * xv3.z); o3.w = fmaf(grs, acc3.w, gi * xv3.w);
        outr[c * 4 + 0] = o0;
        outr[c * 4 + 1] = o1;
        outr[c * 4 + 2] = o2;
        outr[c * 4 + 3] = o3;
    }
}

extern "C" void kernel_launch(void* const* d_in, const int* in_sizes, int n_in,
                              void* d_out, int out_size, void* d_ws, size_t ws_size,
                              hipStream_t stream) {
    const float* x   = (const float*)d_in[0];
    const float* mem = (const float*)d_in[1];
    const float* gw  = (const float*)d_in[2];
    const float* gb  = (const float*)d_in[3];
    float* out = (float*)d_out;
    int n = in_sizes[0] / D;   // number of rows

    int grid = (n + 255) / 256;
    gmm_kernel<<<grid, 256, 0, stream>>>(x, mem, gw, gb, out, n);
}

// Round 10
// 1381.832 us; speedup vs baseline: 17.2678x; 1.0348x over previous
//
#include <hip/hip_runtime.h>

#define D 128
#define M 64            // memory slots
#define MP 80           // padded B1 columns: 64 mem + 1 gate (gw) + 15 zero
#define LDH 136         // ushort stride per slot row in LDS (272B = 17*16B, 2-way bank max)
#define PSTRIDE 68      // float stride of P rows (272B, 16B-aligned)

typedef short s8v __attribute__((ext_vector_type(8)));   // 8 bf16 in 4 VGPRs
typedef float f4v __attribute__((ext_vector_type(4)));   // MFMA accum

// Truncation split f32 -> bf16_hi + bf16_lo. hi = top 16 bits (exact same-sign
// truncation); r = f - hi is exact in f32; lo = truncate(r). Dropped lo*lo MFMA
// term is ~2^-16 relative -> sim error ~1e-4 << 0.0156 tolerance.
__device__ inline void split8(float4 a, float4 b, s8v& hi, s8v& lo) {
    float f[8] = {a.x, a.y, a.z, a.w, b.x, b.y, b.z, b.w};
#pragma unroll
    for (int i = 0; i < 8; ++i) {
        unsigned u = __float_as_uint(f[i]);
        unsigned hb = u & 0xFFFF0000u;
        float r = f[i] - __uint_as_float(hb);
        hi[i] = (short)(hb >> 16);
        lo[i] = (short)(__float_as_uint(r) >> 16);
    }
}

#define MFMA(a, b, c) __builtin_amdgcn_mfma_f32_16x16x32_bf16((a), (b), (c), 0, 0, 0)

__global__ __launch_bounds__(256, 2) void gmm_kernel(
    const float* __restrict__ x, const float* __restrict__ mem,
    const float* __restrict__ gw, const float* __restrict__ gb,
    float* __restrict__ out, int n)
{
    // B1 operand (mem rows + gate column), split bf16, staged once per block.
    __shared__ __align__(16) unsigned short sm_hi[MP][LDH];
    __shared__ __align__(16) unsigned short sm_lo[MP][LDH];
    // wave-private P bounce buffers (C-layout -> A-layout re-tiling)
    __shared__ __align__(16) float pbuf[4][16][PSTRIDE];

    const int lane = threadIdx.x & 63;
    const int c = lane & 15;        // MFMA col / A-row index
    const int h = lane >> 4;        // MFMA k-group
    const int wid = threadIdx.x >> 6;

    // ---- stage mem/gw (split to bf16 hi/lo) into LDS; rows 65..79 zero ----
    for (int idx = threadIdx.x; idx < MP * 4; idx += 256) {
        int r = idx >> 2, q = idx & 3;          // row, 32-float quarter
        float4 v[8];
        if (r < M) {
            const float4* src = (const float4*)(mem + r * D + q * 32);
#pragma unroll
            for (int i = 0; i < 8; ++i) v[i] = src[i];
        } else if (r == M) {
            const float4* src = (const float4*)(gw + q * 32);
#pragma unroll
            for (int i = 0; i < 8; ++i) v[i] = src[i];
        } else {
#pragma unroll
            for (int i = 0; i < 8; ++i) v[i] = make_float4(0.f, 0.f, 0.f, 0.f);
        }
#pragma unroll
        for (int i = 0; i < 4; ++i) {
            s8v hv, lv;
            split8(v[i * 2], v[i * 2 + 1], hv, lv);
            *(s8v*)&sm_hi[r][q * 32 + i * 8] = hv;
            *(s8v*)&sm_lo[r][q * 32 + i * 8] = lv;
        }
    }

    // ---- load pass-2 B (mem, k=slot, col=d) into 128 persistent VGPRs ----
    // B-frag lane layout: col = c + 16*nt, k = 32*ks + 8*h + j
    s8v b2h[2][8], b2l[2][8];
#pragma unroll
    for (int ks = 0; ks < 2; ++ks)
#pragma unroll
        for (int nt = 0; nt < 8; ++nt) {
            float f[8];
#pragma unroll
            for (int j = 0; j < 8; ++j)
                f[j] = mem[(ks * 32 + h * 8 + j) * D + (c + nt * 16)];
            split8(make_float4(f[0], f[1], f[2], f[3]),
                   make_float4(f[4], f[5], f[6], f[7]),
                   b2h[ks][nt], b2l[ks][nt]);
        }

    __syncthreads();   // only barrier; waves run independent tile loops after

    const float gb0 = gb[0];
    float* pmy = &pbuf[wid][0][0];

    const int wave = (blockIdx.x << 2) | wid;
    const int nwaves = gridDim.x << 2;
    const int ntiles = (n + 15) >> 4;

#pragma unroll 1
    for (int t = wave; t < ntiles; t += nwaves) {
        const int base = t << 4;

        // ---- pass 1: C1[nt] = x-tile @ (mem^T | gw | 0), 16x16x32 bf16 x3 ----
        f4v c1[5];
#pragma unroll
        for (int nt = 0; nt < 5; ++nt) c1[nt] = (f4v){0.f, 0.f, 0.f, 0.f};

        int xrow = base + c; if (xrow >= n) xrow = n - 1;   // tail clamp
        const float* xp = x + (size_t)xrow * D;
#pragma unroll
        for (int ks = 0; ks < 4; ++ks) {
            const float4* xv = (const float4*)(xp + ks * 32 + h * 8);
            s8v ah, al;
            split8(xv[0], xv[1], ah, al);
#pragma unroll
            for (int nt = 0; nt < 5; ++nt) {
                s8v bh = *(const s8v*)&sm_hi[c + nt * 16][ks * 32 + h * 8];
                s8v bl = *(const s8v*)&sm_lo[c + nt * 16][ks * 32 + h * 8];
                c1[nt] = MFMA(ah, bh, c1[nt]);
                c1[nt] = MFMA(ah, bl, c1[nt]);
                c1[nt] = MFMA(al, bh, c1[nt]);
            }
        }

        // ---- softmax over 64 slots (C layout: row=4h+reg, slot=c+16nt) ----
        float ge[4];
#pragma unroll
        for (int reg = 0; reg < 4; ++reg) {
            float m0 = fmaxf(fmaxf(c1[0][reg], c1[1][reg]),
                             fmaxf(c1[2][reg], c1[3][reg]));
#pragma unroll
            for (int s = 1; s < 16; s <<= 1) m0 = fmaxf(m0, __shfl_xor(m0, s));
            float p0 = __expf(c1[0][reg] - m0), p1 = __expf(c1[1][reg] - m0);
            float p2 = __expf(c1[2][reg] - m0), p3 = __expf(c1[3][reg] - m0);
            float s0 = (p0 + p1) + (p2 + p3);
#pragma unroll
            for (int s = 1; s < 16; s <<= 1) s0 += __shfl_xor(s0, s);
            float inv = 1.0f / s0;
            int row = h * 4 + reg;               // write normalized attn
            pmy[row * PSTRIDE + c +  0] = p0 * inv;
            pmy[row * PSTRIDE + c + 16] = p1 * inv;
            pmy[row * PSTRIDE + c + 32] = p2 * inv;
            pmy[row * PSTRIDE + c + 48] = p3 * inv;
            // gate dot lives in col 64 (c==0 lanes); add bias, sigmoid
            ge[reg] = 1.0f / (1.0f + __expf(-(c1[4][reg] + gb0)));
        }
#pragma unroll
        for (int reg = 0; reg < 4; ++reg)
            ge[reg] = __shfl(ge[reg], lane & 48);   // broadcast from c==0 lane

        // ---- re-read P in A-frag layout (row=c, k=32ks+8h+j), split ----
        s8v pah[2], pal[2];
#pragma unroll
        for (int ks = 0; ks < 2; ++ks) {
            const float* pr = &pmy[c * PSTRIDE + ks * 32 + h * 8];
            split8(*(const float4*)pr, *(const float4*)(pr + 4),
                   pah[ks], pal[ks]);
        }

        // ---- pass 2: C2[nt] = P @ mem ----
        f4v c2[8];
#pragma unroll
        for (int nt = 0; nt < 8; ++nt) c2[nt] = (f4v){0.f, 0.f, 0.f, 0.f};
#pragma unroll
        for (int ks = 0; ks < 2; ++ks)
#pragma unroll
            for (int nt = 0; nt < 8; ++nt) {
                c2[nt] = MFMA(pah[ks], b2h[ks][nt], c2[nt]);
                c2[nt] = MFMA(pah[ks], b2l[ks][nt], c2[nt]);
                c2[nt] = MFMA(pal[ks], b2h[ks][nt], c2[nt]);
            }

        // ---- epilogue: out = g*read + (1-g)*x  (row=base+4h+reg, d=c+16nt) ----
#pragma unroll
        for (int reg = 0; reg < 4; ++reg) {
            int grow = base + h * 4 + reg;
            bool ok = grow < n;
            const float* xrp = x + (size_t)(ok ? grow : 0) * D + c;
            float* orp = out + (size_t)grow * D + c;
            float g = ge[reg], gi = 1.0f - g;
#pragma unroll
            for (int nt = 0; nt < 8; ++nt) {
                float xv = xrp[nt * 16];
                float o = g * c2[nt][reg] + gi * xv;
                if (ok) orp[nt * 16] = o;
            }
        }
    }
}

extern "C" void kernel_launch(void* const* d_in, const int* in_sizes, int n_in,
                              void* d_out, int out_size, void* d_ws, size_t ws_size,
                              hipStream_t stream) {
    const float* x   = (const float*)d_in[0];
    const float* mem = (const float*)d_in[1];
    const float* gw  = (const float*)d_in[2];
    const float* gb  = (const float*)d_in[3];
    float* out = (float*)d_out;
    int n = in_sizes[0] / D;   // number of rows

    // 512 blocks x 4 waves: exactly 2 blocks/CU resident (61KB LDS each),
    // persistent grid-stride over 16-row tiles.
    gmm_kernel<<<512, 256, 0, stream>>>(x, mem, gw, gb, out, n);
}